// Round 8
// baseline (218.760 us; speedup 1.0000x reference)
//
#include <hip/hip_runtime.h>
#include <math.h>

#define NSLOT 256
#define HWN   16384
#define D_    256
#define BB    4
#define NSEL  768
#define NPOS  512
#define NHEAD 8
#define NQ    4      // quarters per slot

// Reduce 8 per-lane values over all 64 lanes simultaneously.
// Returns: full 64-lane sum of p[h], where h = (lane>>3)&7 for this lane.
__device__ __forceinline__ float reduce8x64(const float p[8], int lane) {
  float v[4];
#pragma unroll
  for (int h = 0; h < 4; h++) {
    float keep = (lane & 32) ? p[h + 4] : p[h];
    float send = (lane & 32) ? p[h] : p[h + 4];
    v[h] = keep + __shfl_xor(send, 32, 64);
  }
  float w[2];
#pragma unroll
  for (int h = 0; h < 2; h++) {
    float keep = (lane & 16) ? v[h + 2] : v[h];
    float send = (lane & 16) ? v[h] : v[h + 2];
    w[h] = keep + __shfl_xor(send, 16, 64);
  }
  float r;
  {
    float keep = (lane & 8) ? w[1] : w[0];
    float send = (lane & 8) ? w[0] : w[1];
    r = keep + __shfl_xor(send, 8, 64);
  }
  r += __shfl_xor(r, 4, 64);
  r += __shfl_xor(r, 2, 64);
  r += __shfl_xor(r, 1, 64);
  return r;
}

// ---------------- Kernel A: per-slot top-768 stable select (1024 thr) ----------------
__global__ __launch_bounds__(1024) void topk_kernel(const float* __restrict__ curio,
                                                    int* __restrict__ feat_sel) {
  __shared__ unsigned int hist[4096];
  __shared__ unsigned int wsum[16];
  __shared__ unsigned long long skey[2048];
  __shared__ int sBstar;
  __shared__ unsigned int sCount;
  int s = blockIdx.x;
  int t = threadIdx.x;
  int wave = t >> 6, lane = t & 63;
  const float* row = curio + (size_t)s * HWN;

  for (int i = t; i < 4096; i += 1024) hist[i] = 0;
  if (t == 0) sCount = 0;
  __syncthreads();
  for (int j = t; j < HWN; j += 1024) {
    unsigned int bits = __float_as_uint(row[j]);   // values in [0,1): bits monotone
    atomicAdd(&hist[bits >> 18], 1u);
  }
  __syncthreads();
  unsigned int cs = hist[t * 4] + hist[t * 4 + 1] + hist[t * 4 + 2] + hist[t * 4 + 3];
  unsigned int v = cs;
#pragma unroll
  for (int off = 1; off < 64; off <<= 1) {
    unsigned int u = __shfl_down(v, off, 64);
    if (lane + off < 64) v += u;       // suffix over lanes >= lane (this wave)
  }
  if (lane == 0) wsum[wave] = v;
  __syncthreads();
  unsigned int above = 0;
  for (int w2 = wave + 1; w2 < 16; w2++) above += wsum[w2];
  unsigned int sufAfter = above + (v - cs);
  if (sufAfter < NSEL && sufAfter + cs >= NSEL) {
    unsigned int local = sufAfter;
    for (int b = t * 4 + 3; b >= t * 4; b--) {
      unsigned int c = hist[b];
      if (local + c >= NSEL) { sBstar = b; break; }
      local += c;
    }
  }
  __syncthreads();
  int bstar = sBstar;
  for (int j = t; j < HWN; j += 1024) {
    unsigned int bits = __float_as_uint(row[j]);
    if ((int)(bits >> 18) >= bstar) {
      unsigned int pos = atomicAdd(&sCount, 1u);
      if (pos < 2048)
        skey[pos] = ((unsigned long long)bits << 14) | (unsigned long long)(16383 - j);
    }
  }
  __syncthreads();
  unsigned int M = sCount;
  int SZ = (M <= 1024) ? 1024 : 2048;
  for (int i = t; i < SZ; i += 1024) if (i >= (int)M) skey[i] = 0ull;
  for (int k = 2; k <= SZ; k <<= 1) {
    for (int j2 = k >> 1; j2 > 0; j2 >>= 1) {
      __syncthreads();
      for (int i = t; i < SZ; i += 1024) {
        int l = i ^ j2;
        if (l > i) {
          unsigned long long a = skey[i], b = skey[l];
          bool dir = ((i & k) == 0);
          if ((a < b) == dir) { skey[i] = b; skey[l] = a; }
        }
      }
    }
  }
  __syncthreads();
  for (int r = t; r < NSEL; r += 1024)
    feat_sel[s * NSEL + r] = 16383 - (int)(skey[r] & 16383ull);
}

// ---------------- Kernel B: q projection + qk = Wk^T q (per slot, 256 thr) ----------------
__global__ __launch_bounds__(256) void qproj_kernel(const float* __restrict__ slots,
                                                    const float* __restrict__ ipw,
                                                    const float* __restrict__ ipb,
                                                    float* __restrict__ qk_g,
                                                    float* __restrict__ qbk_g) {
  __shared__ float srow[D_];
  __shared__ float qrow[D_];
  int s = blockIdx.x, t = threadIdx.x;
  srow[t] = slots[s * D_ + t];
  __syncthreads();
  {
    const float* wq = ipw + (size_t)t * D_;
    float acc = ipb[t];
    for (int d = 0; d < D_; d++) acc += srow[d] * wq[d];
    qrow[t] = acc * 0.17677669529663689f;  // 1/sqrt(32)
  }
  __syncthreads();
  for (int h = 0; h < NHEAD; h++) {
    const float* wkbase = ipw + (size_t)(D_ + h * 32) * D_ + t;
    float a = 0.f;
    for (int e = 0; e < 32; e++) a += qrow[h * 32 + e] * wkbase[(size_t)e * D_];
    qk_g[((size_t)s * NHEAD + h) * D_ + t] = a;
  }
  if (t < NHEAD) {
    float a = 0.f;
    for (int e = 0; e < 32; e++) a += qrow[t * 32 + e] * ipb[D_ + t * 32 + e];
    qbk_g[s * NHEAD + t] = a;
  }
}

// ---------------- Kernel C: aff + fused PV partials. grid = (slot, quarter), 512 thr ----------------
// Block (s, q) handles local rows r=0..191 (global n = q + 4r): r<128 pos, else neg.
// Wave w: pos rows [16w, 16w+16), neg rows 128+[8w, 8w+8), processed in PAIRS.
// __launch_bounds__(512,4): 4 blocks/CU -> 32 waves/CU, VGPR cap 64 (R7 compiled to 60).
__global__ __launch_bounds__(512, 4) void aff_pv_kernel(
    const float* __restrict__ features, const float* __restrict__ posenc,
    const int* __restrict__ batch_idx, const int* __restrict__ feat_sel,
    const float* __restrict__ qk_g, const float* __restrict__ qbk_g,
    float* __restrict__ fbar_part,    // [256][4][8][256]
    float* __restrict__ expsum_part,  // [256][4][8]
    float* __restrict__ stat_part,    // [256][4][2]
    float* __restrict__ aff2_g) {     // [256][768]
  __shared__ float qks[NHEAD][D_];    // 8 KB
  __shared__ float fbar[NHEAD][D_];   // 8 KB
  __shared__ float wtile[8][2][8];    // 0.5 KB
  __shared__ int   sfsel[192];
  __shared__ float esums[8][NHEAD];
  __shared__ float sstat[8][2];
  __shared__ float qbkmean_s;

  int b = blockIdx.x, s = b >> 2, quar = b & 3;
  int t = threadIdx.x, w = t >> 6, lane = t & 63;
  int bi = batch_idx[s];

  for (int i = t; i < NHEAD * D_; i += 512) {
    ((float*)qks)[i] = qk_g[(size_t)s * (NHEAD * D_) + i];
    ((float*)fbar)[i] = 0.f;
  }
  if (t < 192) sfsel[t] = feat_sel[s * NSEL + quar + 4 * t];
  if (t == 0) {
    float m = 0.f;
    for (int h = 0; h < NHEAD; h++) m += qbk_g[s * NHEAD + h];
    qbkmean_s = m * 0.125f;
  }
  __syncthreads();
  float qbkmean = qbkmean_s;

  float acc[NHEAD][4];
#pragma unroll
  for (int h = 0; h < NHEAD; h++)
#pragma unroll
    for (int c = 0; c < 4; c++) acc[h][c] = 0.f;
  float esum = 0.f;              // valid on lanes with (lane&7)==0; head = lane>>3
  float st_s = 0.f, st_q = 0.f;  // valid on lane 0

  // ---- pos rows: aff + PV, 2 rows per iteration
  for (int r0 = 0; r0 < 16; r0 += 2) {
    int rA = w * 16 + r0, rB = rA + 1;
    int idxA = sfsel[rA], idxB = sfsel[rB];
    size_t baseA = ((size_t)idxA * BB + bi) * D_ + (size_t)(lane * 4);
    size_t baseB = ((size_t)idxB * BB + bi) * D_ + (size_t)(lane * 4);
    const float4 fA = *(const float4*)(features + baseA);
    const float4 pA = *(const float4*)(posenc + baseA);
    const float4 fB = *(const float4*)(features + baseB);
    const float4 pB = *(const float4*)(posenc + baseB);
    float4 kA, kB;
    kA.x = fA.x + pA.x; kA.y = fA.y + pA.y; kA.z = fA.z + pA.z; kA.w = fA.w + pA.w;
    kB.x = fB.x + pB.x; kB.y = fB.y + pB.y; kB.z = fB.z + pB.z; kB.w = fB.w + pB.w;
    float ppA[NHEAD], ppB[NHEAD];
#pragma unroll
    for (int h = 0; h < NHEAD; h++) {
      const float4 qw = *(const float4*)&qks[h][lane * 4];
      ppA[h] = kA.x * qw.x + kA.y * qw.y + kA.z * qw.z + kA.w * qw.w;
      ppB[h] = kB.x * qw.x + kB.y * qw.y + kB.z * qw.z + kB.w * qw.w;
    }
    float rsA = reduce8x64(ppA, lane);
    float rsB = reduce8x64(ppB, lane);
    float eA = __expf(rsA);
    float eB = __expf(rsB);
    if ((lane & 7) == 0) {
      int h = lane >> 3;
      wtile[w][0][h] = eA;
      wtile[w][1][h] = eB;
      esum += eA + eB;
    }
    float tA = rsA, tB = rsB;
    tA += __shfl_xor(tA, 8, 64);  tB += __shfl_xor(tB, 8, 64);
    tA += __shfl_xor(tA, 16, 64); tB += __shfl_xor(tB, 16, 64);
    tA += __shfl_xor(tA, 32, 64); tB += __shfl_xor(tB, 32, 64);
    if (lane == 0) {
      float a2A = tA * 0.125f + qbkmean;
      float a2B = tB * 0.125f + qbkmean;
      aff2_g[s * NSEL + quar + 4 * rA] = a2A;
      aff2_g[s * NSEL + quar + 4 * rB] = a2B;
      st_s += a2A + a2B; st_q += a2A * a2A + a2B * a2B;
    }
    // PV: weights broadcast from wtile (same-wave LDS, no barrier needed)
    {
      const float4 w0 = *(const float4*)&wtile[w][0][0];
      const float4 w1 = *(const float4*)&wtile[w][0][4];
      acc[0][0] += w0.x * fA.x; acc[0][1] += w0.x * fA.y; acc[0][2] += w0.x * fA.z; acc[0][3] += w0.x * fA.w;
      acc[1][0] += w0.y * fA.x; acc[1][1] += w0.y * fA.y; acc[1][2] += w0.y * fA.z; acc[1][3] += w0.y * fA.w;
      acc[2][0] += w0.z * fA.x; acc[2][1] += w0.z * fA.y; acc[2][2] += w0.z * fA.z; acc[2][3] += w0.z * fA.w;
      acc[3][0] += w0.w * fA.x; acc[3][1] += w0.w * fA.y; acc[3][2] += w0.w * fA.z; acc[3][3] += w0.w * fA.w;
      acc[4][0] += w1.x * fA.x; acc[4][1] += w1.x * fA.y; acc[4][2] += w1.x * fA.z; acc[4][3] += w1.x * fA.w;
      acc[5][0] += w1.y * fA.x; acc[5][1] += w1.y * fA.y; acc[5][2] += w1.y * fA.z; acc[5][3] += w1.y * fA.w;
      acc[6][0] += w1.z * fA.x; acc[6][1] += w1.z * fA.y; acc[6][2] += w1.z * fA.z; acc[6][3] += w1.z * fA.w;
      acc[7][0] += w1.w * fA.x; acc[7][1] += w1.w * fA.y; acc[7][2] += w1.w * fA.z; acc[7][3] += w1.w * fA.w;
    }
    {
      const float4 w0 = *(const float4*)&wtile[w][1][0];
      const float4 w1 = *(const float4*)&wtile[w][1][4];
      acc[0][0] += w0.x * fB.x; acc[0][1] += w0.x * fB.y; acc[0][2] += w0.x * fB.z; acc[0][3] += w0.x * fB.w;
      acc[1][0] += w0.y * fB.x; acc[1][1] += w0.y * fB.y; acc[1][2] += w0.y * fB.z; acc[1][3] += w0.y * fB.w;
      acc[2][0] += w0.z * fB.x; acc[2][1] += w0.z * fB.y; acc[2][2] += w0.z * fB.z; acc[2][3] += w0.z * fB.w;
      acc[3][0] += w0.w * fB.x; acc[3][1] += w0.w * fB.y; acc[3][2] += w0.w * fB.z; acc[3][3] += w0.w * fB.w;
      acc[4][0] += w1.x * fB.x; acc[4][1] += w1.x * fB.y; acc[4][2] += w1.x * fB.z; acc[4][3] += w1.x * fB.w;
      acc[5][0] += w1.y * fB.x; acc[5][1] += w1.y * fB.y; acc[5][2] += w1.y * fB.z; acc[5][3] += w1.y * fB.w;
      acc[6][0] += w1.z * fB.x; acc[6][1] += w1.z * fB.y; acc[6][2] += w1.z * fB.z; acc[6][3] += w1.z * fB.w;
      acc[7][0] += w1.w * fB.x; acc[7][1] += w1.w * fB.y; acc[7][2] += w1.w * fB.z; acc[7][3] += w1.w * fB.w;
    }
  }

  // ---- neg rows: aff only, 2 rows per iteration
  for (int r0 = 0; r0 < 8; r0 += 2) {
    int rA = 128 + w * 8 + r0, rB = rA + 1;
    int idxA = sfsel[rA], idxB = sfsel[rB];
    size_t baseA = ((size_t)idxA * BB + bi) * D_ + (size_t)(lane * 4);
    size_t baseB = ((size_t)idxB * BB + bi) * D_ + (size_t)(lane * 4);
    const float4 fA = *(const float4*)(features + baseA);
    const float4 pA = *(const float4*)(posenc + baseA);
    const float4 fB = *(const float4*)(features + baseB);
    const float4 pB = *(const float4*)(posenc + baseB);
    float4 kA, kB;
    kA.x = fA.x + pA.x; kA.y = fA.y + pA.y; kA.z = fA.z + pA.z; kA.w = fA.w + pA.w;
    kB.x = fB.x + pB.x; kB.y = fB.y + pB.y; kB.z = fB.z + pB.z; kB.w = fB.w + pB.w;
    float ppA[NHEAD], ppB[NHEAD];
#pragma unroll
    for (int h = 0; h < NHEAD; h++) {
      const float4 qw = *(const float4*)&qks[h][lane * 4];
      ppA[h] = kA.x * qw.x + kA.y * qw.y + kA.z * qw.z + kA.w * qw.w;
      ppB[h] = kB.x * qw.x + kB.y * qw.y + kB.z * qw.z + kB.w * qw.w;
    }
    float rsA = reduce8x64(ppA, lane);
    float rsB = reduce8x64(ppB, lane);
    float tA = rsA, tB = rsB;
    tA += __shfl_xor(tA, 8, 64);  tB += __shfl_xor(tB, 8, 64);
    tA += __shfl_xor(tA, 16, 64); tB += __shfl_xor(tB, 16, 64);
    tA += __shfl_xor(tA, 32, 64); tB += __shfl_xor(tB, 32, 64);
    if (lane == 0) {
      float a2A = tA * 0.125f + qbkmean;
      float a2B = tB * 0.125f + qbkmean;
      aff2_g[s * NSEL + quar + 4 * rA] = a2A;
      aff2_g[s * NSEL + quar + 4 * rB] = a2B;
      st_s += a2A + a2B; st_q += a2A * a2A + a2B * a2B;
    }
  }

  // ---- combine partials
  if ((lane & 7) == 0) esums[w][lane >> 3] = esum;
  if (lane == 0) { sstat[w][0] = st_s; sstat[w][1] = st_q; }
#pragma unroll
  for (int hh = 0; hh < NHEAD; hh++) {
    int h = (hh + w) & 7;  // stagger
    atomicAdd(&fbar[h][lane * 4 + 0], acc[h][0]);
    atomicAdd(&fbar[h][lane * 4 + 1], acc[h][1]);
    atomicAdd(&fbar[h][lane * 4 + 2], acc[h][2]);
    atomicAdd(&fbar[h][lane * 4 + 3], acc[h][3]);
  }
  __syncthreads();
  if (t < NHEAD) {
    float e2 = 0.f;
    for (int w2 = 0; w2 < 8; w2++) e2 += esums[w2][t];
    expsum_part[b * NHEAD + t] = e2;
  } else if (t == NHEAD) {
    float a = 0.f, q = 0.f;
    for (int w2 = 0; w2 < 8; w2++) { a += sstat[w2][0]; q += sstat[w2][1]; }
    stat_part[b * 2 + 0] = a;
    stat_part[b * 2 + 1] = q;
  }
  ((float4*)(fbar_part + (size_t)b * (NHEAD * D_)))[t] = ((float4*)fbar)[t];
}

// ---------------- Kernel D: combine partials + Wv + out-proj + LN + norm_aff ----------------
__global__ __launch_bounds__(1024) void finish_kernel(
    const float* __restrict__ slots,
    const float* __restrict__ expsum_part, const float* __restrict__ stat_part,
    const float* __restrict__ aff2_g, const float* __restrict__ fbar_part,
    const float* __restrict__ ipw, const float* __restrict__ ipb,
    const float* __restrict__ wout, const float* __restrict__ bout,
    const float* __restrict__ lnw, const float* __restrict__ lnb,
    float* __restrict__ slots_new, float* __restrict__ norm_aff) {
  __shared__ float fbar[NHEAD][D_];
  __shared__ float srow[D_];
  __shared__ float outv[D_];
  __shared__ float pq[1024];
  __shared__ float redS[4], redQ[4];
  int s = blockIdx.x, t = threadIdx.x, wave = t >> 6, lane = t & 63;

  // LN stats for norm_aff (uniform loads over 4 quarter-partials)
  float st0 = stat_part[s * 8 + 0] + stat_part[s * 8 + 2] + stat_part[s * 8 + 4] + stat_part[s * 8 + 6];
  float st1 = stat_part[s * 8 + 1] + stat_part[s * 8 + 3] + stat_part[s * 8 + 5] + stat_part[s * 8 + 7];
  float mean_a = st0 * (1.0f / NSEL);
  float var_a = st1 * (1.0f / NSEL) - mean_a * mean_a;
  float rstd_a = rsqrtf(var_a + 1e-5f);
  if (t < NSEL) norm_aff[(size_t)t * NSLOT + s] = (aff2_g[s * NSEL + t] - mean_a) * rstd_a;

  if (t < 512) {
    int h = t >> 6;  // fbar layout [8][256]: 64 float4s per head
    float inv = 1.0f / (expsum_part[s * 32 + h] + expsum_part[s * 32 + 8 + h] +
                        expsum_part[s * 32 + 16 + h] + expsum_part[s * 32 + 24 + h]);
    const float4* fp = (const float4*)(fbar_part + (size_t)s * (4 * NHEAD * D_));
    const float4 a = fp[t];
    const float4 c = fp[t + 512];
    const float4 d = fp[t + 1024];
    const float4 e = fp[t + 1536];
    float4 r;
    r.x = (a.x + c.x + d.x + e.x) * inv; r.y = (a.y + c.y + d.y + e.y) * inv;
    r.z = (a.z + c.z + d.z + e.z) * inv; r.w = (a.w + c.w + d.w + e.w) * inv;
    ((float4*)fbar)[t] = r;
  }
  if (t < 64) ((float4*)srow)[t] = ((const float4*)(slots + (size_t)s * D_))[t];
  __syncthreads();

  // out = Wv . fbar(h) + bv  (quarter-dots)
  {
    int o = t >> 2, part = t & 3, h = o >> 5;
    const float4* wv = (const float4*)(ipw + (size_t)(2 * D_ + o) * D_ + part * 64);
    float a = 0.f;
#pragma unroll
    for (int i = 0; i < 16; i++) {
      float4 w = wv[i];
      int d = part * 64 + i * 4;
      a += fbar[h][d] * w.x + fbar[h][d + 1] * w.y + fbar[h][d + 2] * w.z + fbar[h][d + 3] * w.w;
    }
    pq[t] = a;
  }
  __syncthreads();
  if (t < D_)
    outv[t] = pq[t * 4] + pq[t * 4 + 1] + pq[t * 4 + 2] + pq[t * 4 + 3] + ipb[2 * D_ + t];
  __syncthreads();

  // slots_new = LN(srow + Wout.outv + bout) * lnw + lnb
  {
    int o = t >> 2, part = t & 3;
    const float4* w4 = (const float4*)(wout + (size_t)o * D_ + part * 64);
    float a = 0.f;
#pragma unroll
    for (int i = 0; i < 16; i++) {
      float4 w = w4[i];
      int d = part * 64 + i * 4;
      a += outv[d] * w.x + outv[d + 1] * w.y + outv[d + 2] * w.z + outv[d + 3] * w.w;
    }
    pq[t] = a;
  }
  __syncthreads();
  float v = 0.f;
  if (t < D_) {
    v = srow[t] + pq[t * 4] + pq[t * 4 + 1] + pq[t * 4 + 2] + pq[t * 4 + 3] + bout[t];
    float ls = v, lq = v * v;
#pragma unroll
    for (int off = 32; off >= 1; off >>= 1) { ls += __shfl_xor(ls, off, 64); lq += __shfl_xor(lq, off, 64); }
    if (lane == 0) { redS[wave] = ls; redQ[wave] = lq; }
  }
  __syncthreads();
  if (t < D_) {
    float tots = redS[0] + redS[1] + redS[2] + redS[3];
    float totq = redQ[0] + redQ[1] + redQ[2] + redQ[3];
    float mean = tots * (1.0f / D_);
    float var = totq * (1.0f / D_) - mean * mean;
    float rstd = rsqrtf(var + 1e-5f);
    slots_new[s * D_ + t] = (v - mean) * rstd * lnw[t] + lnb[t];
  }
}

extern "C" void kernel_launch(void* const* d_in, const int* in_sizes, int n_in,
                              void* d_out, int out_size, void* d_ws, size_t ws_size,
                              hipStream_t stream) {
  const float* slots    = (const float*)d_in[0];
  const float* features = (const float*)d_in[1];
  const float* posenc   = (const float*)d_in[2];
  const float* curio    = (const float*)d_in[3];
  const int*   batch_idx= (const int*)d_in[4];
  const float* ipw      = (const float*)d_in[5];
  const float* ipb      = (const float*)d_in[6];
  const float* wout     = (const float*)d_in[7];
  const float* bout     = (const float*)d_in[8];
  const float* lnw      = (const float*)d_in[9];
  const float* lnb      = (const float*)d_in[10];

  char* ws = (char*)d_ws;
  size_t off = 0;
  int*   feat_sel    = (int*)(ws + off);   off += 256 * 768 * 4;           // 786432
  float* qk_g        = (float*)(ws + off); off += 256 * 8 * 256 * 4;       // 2097152
  float* qbk_g       = (float*)(ws + off); off += 256 * 8 * 4;             // 8192
  float* fbar_part   = (float*)(ws + off); off += 256 * NQ * 8 * 256 * 4;  // 8388608
  float* expsum_part = (float*)(ws + off); off += 256 * NQ * 8 * 4;        // 32768
  float* stat_part   = (float*)(ws + off); off += 256 * NQ * 2 * 4;        // 8192
  float* aff2_g      = (float*)(ws + off); off += 256 * 768 * 4;           // 786432

  float* out_f = (float*)d_out;  // [0,65536) slots_new, [65536,262144) norm_aff

  topk_kernel<<<NSLOT, 1024, 0, stream>>>(curio, feat_sel);
  qproj_kernel<<<NSLOT, 256, 0, stream>>>(slots, ipw, ipb, qk_g, qbk_g);
  aff_pv_kernel<<<NSLOT * NQ, 512, 0, stream>>>(features, posenc, batch_idx, feat_sel,
                                                qk_g, qbk_g, fbar_part, expsum_part,
                                                stat_part, aff2_g);
  finish_kernel<<<NSLOT, 1024, 0, stream>>>(slots, expsum_part, stat_part, aff2_g,
                                            fbar_part, ipw, ipb, wout, bout, lnw, lnb,
                                            out_f, out_f + 65536);
}

// Round 9
// 177.868 us; speedup vs baseline: 1.2299x; 1.2299x over previous
//
#include <hip/hip_runtime.h>
#include <math.h>

#define NSLOT 256
#define HWN   16384
#define D_    256
#define BB    4
#define NSEL  768
#define NPOS  512
#define NHEAD 8

// Reduce 8 per-lane values over all 64 lanes simultaneously.
// Returns: full 64-lane sum of p[h], where h = (lane>>3)&7 for this lane.
__device__ __forceinline__ float reduce8x64(const float p[8], int lane) {
  float v[4];
#pragma unroll
  for (int h = 0; h < 4; h++) {
    float keep = (lane & 32) ? p[h + 4] : p[h];
    float send = (lane & 32) ? p[h] : p[h + 4];
    v[h] = keep + __shfl_xor(send, 32, 64);
  }
  float w[2];
#pragma unroll
  for (int h = 0; h < 2; h++) {
    float keep = (lane & 16) ? v[h + 2] : v[h];
    float send = (lane & 16) ? v[h] : v[h + 2];
    w[h] = keep + __shfl_xor(send, 16, 64);
  }
  float r;
  {
    float keep = (lane & 8) ? w[1] : w[0];
    float send = (lane & 8) ? w[0] : w[1];
    r = keep + __shfl_xor(send, 8, 64);
  }
  r += __shfl_xor(r, 4, 64);
  r += __shfl_xor(r, 2, 64);
  r += __shfl_xor(r, 1, 64);
  return r;
}

// ---------------- Kernel A: per-slot top-768 stable select (1024 thr) ----------------
__global__ __launch_bounds__(1024) void topk_kernel(const float* __restrict__ curio,
                                                    int* __restrict__ feat_sel) {
  __shared__ unsigned int hist[4096];
  __shared__ unsigned int wsum[16];
  __shared__ unsigned long long skey[2048];
  __shared__ int sBstar;
  __shared__ unsigned int sCount;
  int s = blockIdx.x;
  int t = threadIdx.x;
  int wave = t >> 6, lane = t & 63;
  const float* row = curio + (size_t)s * HWN;

  for (int i = t; i < 4096; i += 1024) hist[i] = 0;
  if (t == 0) sCount = 0;
  __syncthreads();
  for (int j = t; j < HWN; j += 1024) {
    unsigned int bits = __float_as_uint(row[j]);   // values in [0,1): bits monotone
    atomicAdd(&hist[bits >> 18], 1u);
  }
  __syncthreads();
  unsigned int cs = hist[t * 4] + hist[t * 4 + 1] + hist[t * 4 + 2] + hist[t * 4 + 3];
  unsigned int v = cs;
#pragma unroll
  for (int off = 1; off < 64; off <<= 1) {
    unsigned int u = __shfl_down(v, off, 64);
    if (lane + off < 64) v += u;       // suffix over lanes >= lane (this wave)
  }
  if (lane == 0) wsum[wave] = v;
  __syncthreads();
  unsigned int above = 0;
  for (int w2 = wave + 1; w2 < 16; w2++) above += wsum[w2];
  unsigned int sufAfter = above + (v - cs);
  if (sufAfter < NSEL && sufAfter + cs >= NSEL) {
    unsigned int local = sufAfter;
    for (int b = t * 4 + 3; b >= t * 4; b--) {
      unsigned int c = hist[b];
      if (local + c >= NSEL) { sBstar = b; break; }
      local += c;
    }
  }
  __syncthreads();
  int bstar = sBstar;
  for (int j = t; j < HWN; j += 1024) {
    unsigned int bits = __float_as_uint(row[j]);
    if ((int)(bits >> 18) >= bstar) {
      unsigned int pos = atomicAdd(&sCount, 1u);
      if (pos < 2048)
        skey[pos] = ((unsigned long long)bits << 14) | (unsigned long long)(16383 - j);
    }
  }
  __syncthreads();
  unsigned int M = sCount;
  int SZ = (M <= 1024) ? 1024 : 2048;
  for (int i = t; i < SZ; i += 1024) if (i >= (int)M) skey[i] = 0ull;
  for (int k = 2; k <= SZ; k <<= 1) {
    for (int j2 = k >> 1; j2 > 0; j2 >>= 1) {
      __syncthreads();
      for (int i = t; i < SZ; i += 1024) {
        int l = i ^ j2;
        if (l > i) {
          unsigned long long a = skey[i], b = skey[l];
          bool dir = ((i & k) == 0);
          if ((a < b) == dir) { skey[i] = b; skey[l] = a; }
        }
      }
    }
  }
  __syncthreads();
  for (int r = t; r < NSEL; r += 1024)
    feat_sel[s * NSEL + r] = 16383 - (int)(skey[r] & 16383ull);
}

// ---------------- Kernel B: q projection + qk = Wk^T q + qksum (per slot, 256 thr) ----------------
__global__ __launch_bounds__(256) void qproj_kernel(const float* __restrict__ slots,
                                                    const float* __restrict__ ipw,
                                                    const float* __restrict__ ipb,
                                                    float* __restrict__ qk_g,
                                                    float* __restrict__ qbk_g,
                                                    float* __restrict__ qksum_g) {
  __shared__ float srow[D_];
  __shared__ float qrow[D_];
  int s = blockIdx.x, t = threadIdx.x;
  srow[t] = slots[s * D_ + t];
  __syncthreads();
  {
    const float* wq = ipw + (size_t)t * D_;
    float acc = ipb[t];
    for (int d = 0; d < D_; d++) acc += srow[d] * wq[d];
    qrow[t] = acc * 0.17677669529663689f;  // 1/sqrt(32)
  }
  __syncthreads();
  float qsum = 0.f;
  for (int h = 0; h < NHEAD; h++) {
    const float* wkbase = ipw + (size_t)(D_ + h * 32) * D_ + t;
    float a = 0.f;
    for (int e = 0; e < 32; e++) a += qrow[h * 32 + e] * wkbase[(size_t)e * D_];
    qk_g[((size_t)s * NHEAD + h) * D_ + t] = a;
    qsum += a;
  }
  qksum_g[s * D_ + t] = qsum;
  if (t < NHEAD) {
    float a = 0.f;
    for (int e = 0; e < 32; e++) a += qrow[t * 32 + e] * ipb[D_ + t * 32 + e];
    qbk_g[s * NHEAD + t] = a;
  }
}

// ---------------- Kernel C: aff + fused PV partials. grid = (slot, half), 512 thr ----------------
// Block (s, half): local rows r=0..383 (global n = half + 2r): r<256 pos, else neg.
// Wave w: pos rows [32w,32w+32), neg rows 256+[16w,16w+16), pairs with 1-deep PREFETCH.
// Neg rows only feed aff2 = mean_h(aff): sum_h k.qk[h] = k.qksum -> one dot + butterfly.
__global__ __launch_bounds__(512, 2) void aff_pv_kernel(
    const float* __restrict__ features, const float* __restrict__ posenc,
    const int* __restrict__ batch_idx, const int* __restrict__ feat_sel,
    const float* __restrict__ qk_g, const float* __restrict__ qbk_g,
    const float* __restrict__ qksum_g,
    float* __restrict__ fbar_part,    // [256][2][8][256]
    float* __restrict__ expsum_part,  // [256][2][8]
    float* __restrict__ stat_part,    // [256][2][2]
    float* __restrict__ aff2_g) {     // [256][768]
  __shared__ float qks[NHEAD][D_];    // 8 KB
  __shared__ float qksum[D_];         // 1 KB
  __shared__ float fbar[NHEAD][D_];   // 8 KB
  __shared__ float wtile[8][2][8];    // 0.5 KB
  __shared__ int   sfsel[392];        // padded: tail prefetch reads [384..391] safely
  __shared__ float esums[8][NHEAD];
  __shared__ float sstat[8][2];
  __shared__ float qbkmean_s;

  int b = blockIdx.x, s = b >> 1, half = b & 1;
  int t = threadIdx.x, w = t >> 6, lane = t & 63;
  int bi = batch_idx[s];

  for (int i = t; i < NHEAD * D_; i += 512) {
    ((float*)qks)[i] = qk_g[(size_t)s * (NHEAD * D_) + i];
    ((float*)fbar)[i] = 0.f;
  }
  if (t < D_) qksum[t] = qksum_g[s * D_ + t];
  if (t < 392) {
    int tt = (t < 384) ? t : 0;
    sfsel[t] = feat_sel[s * NSEL + half + 2 * tt];
  }
  if (t == 0) {
    float m = 0.f;
    for (int h = 0; h < NHEAD; h++) m += qbk_g[s * NHEAD + h];
    qbkmean_s = m * 0.125f;
  }
  __syncthreads();
  float qbkmean = qbkmean_s;
  const float4 qs4 = *(const float4*)&qksum[lane * 4];
  size_t lofs = (size_t)(lane * 4);

  float acc[NHEAD][4];
#pragma unroll
  for (int h = 0; h < NHEAD; h++)
#pragma unroll
    for (int c = 0; c < 4; c++) acc[h][c] = 0.f;
  float esum = 0.f;              // valid on lanes with (lane&7)==0; head = lane>>3
  float st_s = 0.f, st_q = 0.f;  // valid on lane 0

  // ---- pos rows: aff + PV, 2 rows/iter, 1-deep prefetch
  float4 fA, pA, fB, pB;
  {
    size_t baseA = ((size_t)sfsel[w * 32] * BB + bi) * D_ + lofs;
    size_t baseB = ((size_t)sfsel[w * 32 + 1] * BB + bi) * D_ + lofs;
    fA = *(const float4*)(features + baseA);
    pA = *(const float4*)(posenc + baseA);
    fB = *(const float4*)(features + baseB);
    pB = *(const float4*)(posenc + baseB);
  }
  for (int r0 = 0; r0 < 32; r0 += 2) {
    // prefetch next pair (last iter reads sfsel[256..257] -> harmless valid row)
    int nA = w * 32 + r0 + 2;
    size_t nbA = ((size_t)sfsel[nA] * BB + bi) * D_ + lofs;
    size_t nbB = ((size_t)sfsel[nA + 1] * BB + bi) * D_ + lofs;
    float4 nfA = *(const float4*)(features + nbA);
    float4 npA = *(const float4*)(posenc + nbA);
    float4 nfB = *(const float4*)(features + nbB);
    float4 npB = *(const float4*)(posenc + nbB);

    float4 kA, kB;
    kA.x = fA.x + pA.x; kA.y = fA.y + pA.y; kA.z = fA.z + pA.z; kA.w = fA.w + pA.w;
    kB.x = fB.x + pB.x; kB.y = fB.y + pB.y; kB.z = fB.z + pB.z; kB.w = fB.w + pB.w;
    float ppA[NHEAD], ppB[NHEAD];
#pragma unroll
    for (int h = 0; h < NHEAD; h++) {
      const float4 qw = *(const float4*)&qks[h][lane * 4];
      ppA[h] = kA.x * qw.x + kA.y * qw.y + kA.z * qw.z + kA.w * qw.w;
      ppB[h] = kB.x * qw.x + kB.y * qw.y + kB.z * qw.z + kB.w * qw.w;
    }
    float rsA = reduce8x64(ppA, lane);
    float rsB = reduce8x64(ppB, lane);
    float eA = __expf(rsA);
    float eB = __expf(rsB);
    if ((lane & 7) == 0) {
      int h = lane >> 3;
      wtile[w][0][h] = eA;
      wtile[w][1][h] = eB;
      esum += eA + eB;
    }
    float tA = rsA, tB = rsB;
    tA += __shfl_xor(tA, 8, 64);  tB += __shfl_xor(tB, 8, 64);
    tA += __shfl_xor(tA, 16, 64); tB += __shfl_xor(tB, 16, 64);
    tA += __shfl_xor(tA, 32, 64); tB += __shfl_xor(tB, 32, 64);
    if (lane == 0) {
      int rA = w * 32 + r0;
      float a2A = tA * 0.125f + qbkmean;
      float a2B = tB * 0.125f + qbkmean;
      aff2_g[s * NSEL + half + 2 * rA] = a2A;
      aff2_g[s * NSEL + half + 2 * (rA + 1)] = a2B;
      st_s += a2A + a2B; st_q += a2A * a2A + a2B * a2B;
    }
    // PV: weights broadcast from wtile (same-wave LDS, no barrier needed)
    {
      const float4 w0 = *(const float4*)&wtile[w][0][0];
      const float4 w1 = *(const float4*)&wtile[w][0][4];
      acc[0][0] += w0.x * fA.x; acc[0][1] += w0.x * fA.y; acc[0][2] += w0.x * fA.z; acc[0][3] += w0.x * fA.w;
      acc[1][0] += w0.y * fA.x; acc[1][1] += w0.y * fA.y; acc[1][2] += w0.y * fA.z; acc[1][3] += w0.y * fA.w;
      acc[2][0] += w0.z * fA.x; acc[2][1] += w0.z * fA.y; acc[2][2] += w0.z * fA.z; acc[2][3] += w0.z * fA.w;
      acc[3][0] += w0.w * fA.x; acc[3][1] += w0.w * fA.y; acc[3][2] += w0.w * fA.z; acc[3][3] += w0.w * fA.w;
      acc[4][0] += w1.x * fA.x; acc[4][1] += w1.x * fA.y; acc[4][2] += w1.x * fA.z; acc[4][3] += w1.x * fA.w;
      acc[5][0] += w1.y * fA.x; acc[5][1] += w1.y * fA.y; acc[5][2] += w1.y * fA.z; acc[5][3] += w1.y * fA.w;
      acc[6][0] += w1.z * fA.x; acc[6][1] += w1.z * fA.y; acc[6][2] += w1.z * fA.z; acc[6][3] += w1.z * fA.w;
      acc[7][0] += w1.w * fA.x; acc[7][1] += w1.w * fA.y; acc[7][2] += w1.w * fA.z; acc[7][3] += w1.w * fA.w;
    }
    {
      const float4 w0 = *(const float4*)&wtile[w][1][0];
      const float4 w1 = *(const float4*)&wtile[w][1][4];
      acc[0][0] += w0.x * fB.x; acc[0][1] += w0.x * fB.y; acc[0][2] += w0.x * fB.z; acc[0][3] += w0.x * fB.w;
      acc[1][0] += w0.y * fB.x; acc[1][1] += w0.y * fB.y; acc[1][2] += w0.y * fB.z; acc[1][3] += w0.y * fB.w;
      acc[2][0] += w0.z * fB.x; acc[2][1] += w0.z * fB.y; acc[2][2] += w0.z * fB.z; acc[2][3] += w0.z * fB.w;
      acc[3][0] += w0.w * fB.x; acc[3][1] += w0.w * fB.y; acc[3][2] += w0.w * fB.z; acc[3][3] += w0.w * fB.w;
      acc[4][0] += w1.x * fB.x; acc[4][1] += w1.x * fB.y; acc[4][2] += w1.x * fB.z; acc[4][3] += w1.x * fB.w;
      acc[5][0] += w1.y * fB.x; acc[5][1] += w1.y * fB.y; acc[5][2] += w1.y * fB.z; acc[5][3] += w1.y * fB.w;
      acc[6][0] += w1.z * fB.x; acc[6][1] += w1.z * fB.y; acc[6][2] += w1.z * fB.z; acc[6][3] += w1.z * fB.w;
      acc[7][0] += w1.w * fB.x; acc[7][1] += w1.w * fB.y; acc[7][2] += w1.w * fB.z; acc[7][3] += w1.w * fB.w;
    }
    fA = nfA; pA = npA; fB = nfB; pB = npB;
  }

  // ---- neg rows: aff2 only via k.qksum, 2 rows/iter, 1-deep prefetch
  {
    int rN = 256 + w * 16;
    size_t baseA = ((size_t)sfsel[rN] * BB + bi) * D_ + lofs;
    size_t baseB = ((size_t)sfsel[rN + 1] * BB + bi) * D_ + lofs;
    fA = *(const float4*)(features + baseA);
    pA = *(const float4*)(posenc + baseA);
    fB = *(const float4*)(features + baseB);
    pB = *(const float4*)(posenc + baseB);
    for (int r0 = 0; r0 < 16; r0 += 2) {
      int nA = rN + r0 + 2;  // last iter: sfsel[384..385] padded -> harmless
      size_t nbA = ((size_t)sfsel[nA] * BB + bi) * D_ + lofs;
      size_t nbB = ((size_t)sfsel[nA + 1] * BB + bi) * D_ + lofs;
      float4 nfA = *(const float4*)(features + nbA);
      float4 npA = *(const float4*)(posenc + nbA);
      float4 nfB = *(const float4*)(features + nbB);
      float4 npB = *(const float4*)(posenc + nbB);

      float4 kA, kB;
      kA.x = fA.x + pA.x; kA.y = fA.y + pA.y; kA.z = fA.z + pA.z; kA.w = fA.w + pA.w;
      kB.x = fB.x + pB.x; kB.y = fB.y + pB.y; kB.z = fB.z + pB.z; kB.w = fB.w + pB.w;
      float sppA = kA.x * qs4.x + kA.y * qs4.y + kA.z * qs4.z + kA.w * qs4.w;
      float sppB = kB.x * qs4.x + kB.y * qs4.y + kB.z * qs4.z + kB.w * qs4.w;
#pragma unroll
      for (int off = 1; off < 64; off <<= 1) {
        sppA += __shfl_xor(sppA, off, 64);
        sppB += __shfl_xor(sppB, off, 64);
      }
      if (lane == 0) {
        int rA = rN + r0;
        float a2A = sppA * 0.125f + qbkmean;
        float a2B = sppB * 0.125f + qbkmean;
        aff2_g[s * NSEL + half + 2 * rA] = a2A;
        aff2_g[s * NSEL + half + 2 * (rA + 1)] = a2B;
        st_s += a2A + a2B; st_q += a2A * a2A + a2B * a2B;
      }
      fA = nfA; pA = npA; fB = nfB; pB = npB;
    }
  }

  // ---- combine partials
  if ((lane & 7) == 0) esums[w][lane >> 3] = esum;
  if (lane == 0) { sstat[w][0] = st_s; sstat[w][1] = st_q; }
#pragma unroll
  for (int h = 0; h < NHEAD; h++) {  // static index (rule #20); bank layout identical
    atomicAdd(&fbar[h][lane * 4 + 0], acc[h][0]);
    atomicAdd(&fbar[h][lane * 4 + 1], acc[h][1]);
    atomicAdd(&fbar[h][lane * 4 + 2], acc[h][2]);
    atomicAdd(&fbar[h][lane * 4 + 3], acc[h][3]);
  }
  __syncthreads();
  if (t < NHEAD) {
    float e2 = 0.f;
    for (int w2 = 0; w2 < 8; w2++) e2 += esums[w2][t];
    expsum_part[b * NHEAD + t] = e2;
  } else if (t == NHEAD) {
    float a = 0.f, q = 0.f;
    for (int w2 = 0; w2 < 8; w2++) { a += sstat[w2][0]; q += sstat[w2][1]; }
    stat_part[b * 2 + 0] = a;
    stat_part[b * 2 + 1] = q;
  }
  ((float4*)(fbar_part + (size_t)b * (NHEAD * D_)))[t] = ((float4*)fbar)[t];
}

// ---------------- Kernel D: combine partials + Wv + out-proj + LN + norm_aff ----------------
__global__ __launch_bounds__(1024) void finish_kernel(
    const float* __restrict__ slots,
    const float* __restrict__ expsum_part, const float* __restrict__ stat_part,
    const float* __restrict__ aff2_g, const float* __restrict__ fbar_part,
    const float* __restrict__ ipw, const float* __restrict__ ipb,
    const float* __restrict__ wout, const float* __restrict__ bout,
    const float* __restrict__ lnw, const float* __restrict__ lnb,
    float* __restrict__ slots_new, float* __restrict__ norm_aff) {
  __shared__ float fbar[NHEAD][D_];
  __shared__ float srow[D_];
  __shared__ float outv[D_];
  __shared__ float pq[1024];
  __shared__ float redS[4], redQ[4];
  int s = blockIdx.x, t = threadIdx.x, wave = t >> 6, lane = t & 63;

  // LN stats for norm_aff (uniform loads)
  float st0 = stat_part[s * 4 + 0] + stat_part[s * 4 + 2];
  float st1 = stat_part[s * 4 + 1] + stat_part[s * 4 + 3];
  float mean_a = st0 * (1.0f / NSEL);
  float var_a = st1 * (1.0f / NSEL) - mean_a * mean_a;
  float rstd_a = rsqrtf(var_a + 1e-5f);
  if (t < NSEL) norm_aff[(size_t)t * NSLOT + s] = (aff2_g[s * NSEL + t] - mean_a) * rstd_a;

  if (t < 512) {
    int h = t >> 6;  // fbar layout [8][256]: 64 float4s per head
    float inv = 1.0f / (expsum_part[s * 16 + h] + expsum_part[s * 16 + 8 + h]);
    const float4 a = ((const float4*)(fbar_part + (size_t)s * 4096))[t];
    const float4 c = ((const float4*)(fbar_part + (size_t)s * 4096 + 2048))[t];
    float4 r;
    r.x = (a.x + c.x) * inv; r.y = (a.y + c.y) * inv;
    r.z = (a.z + c.z) * inv; r.w = (a.w + c.w) * inv;
    ((float4*)fbar)[t] = r;
  }
  if (t < 64) ((float4*)srow)[t] = ((const float4*)(slots + (size_t)s * D_))[t];
  __syncthreads();

  // out = Wv . fbar(h) + bv  (quarter-dots)
  {
    int o = t >> 2, part = t & 3, h = o >> 5;
    const float4* wv = (const float4*)(ipw + (size_t)(2 * D_ + o) * D_ + part * 64);
    float a = 0.f;
#pragma unroll
    for (int i = 0; i < 16; i++) {
      float4 w = wv[i];
      int d = part * 64 + i * 4;
      a += fbar[h][d] * w.x + fbar[h][d + 1] * w.y + fbar[h][d + 2] * w.z + fbar[h][d + 3] * w.w;
    }
    pq[t] = a;
  }
  __syncthreads();
  if (t < D_)
    outv[t] = pq[t * 4] + pq[t * 4 + 1] + pq[t * 4 + 2] + pq[t * 4 + 3] + ipb[2 * D_ + t];
  __syncthreads();

  // slots_new = LN(srow + Wout.outv + bout) * lnw + lnb
  {
    int o = t >> 2, part = t & 3;
    const float4* w4 = (const float4*)(wout + (size_t)o * D_ + part * 64);
    float a = 0.f;
#pragma unroll
    for (int i = 0; i < 16; i++) {
      float4 w = w4[i];
      int d = part * 64 + i * 4;
      a += outv[d] * w.x + outv[d + 1] * w.y + outv[d + 2] * w.z + outv[d + 3] * w.w;
    }
    pq[t] = a;
  }
  __syncthreads();
  float v = 0.f;
  if (t < D_) {
    v = srow[t] + pq[t * 4] + pq[t * 4 + 1] + pq[t * 4 + 2] + pq[t * 4 + 3] + bout[t];
    float ls = v, lq = v * v;
#pragma unroll
    for (int off = 32; off >= 1; off >>= 1) { ls += __shfl_xor(ls, off, 64); lq += __shfl_xor(lq, off, 64); }
    if (lane == 0) { redS[wave] = ls; redQ[wave] = lq; }
  }
  __syncthreads();
  if (t < D_) {
    float tots = redS[0] + redS[1] + redS[2] + redS[3];
    float totq = redQ[0] + redQ[1] + redQ[2] + redQ[3];
    float mean = tots * (1.0f / D_);
    float var = totq * (1.0f / D_) - mean * mean;
    float rstd = rsqrtf(var + 1e-5f);
    slots_new[s * D_ + t] = (v - mean) * rstd * lnw[t] + lnb[t];
  }
}

extern "C" void kernel_launch(void* const* d_in, const int* in_sizes, int n_in,
                              void* d_out, int out_size, void* d_ws, size_t ws_size,
                              hipStream_t stream) {
  const float* slots    = (const float*)d_in[0];
  const float* features = (const float*)d_in[1];
  const float* posenc   = (const float*)d_in[2];
  const float* curio    = (const float*)d_in[3];
  const int*   batch_idx= (const int*)d_in[4];
  const float* ipw      = (const float*)d_in[5];
  const float* ipb      = (const float*)d_in[6];
  const float* wout     = (const float*)d_in[7];
  const float* bout     = (const float*)d_in[8];
  const float* lnw      = (const float*)d_in[9];
  const float* lnb      = (const float*)d_in[10];

  char* ws = (char*)d_ws;
  size_t off = 0;
  int*   feat_sel    = (int*)(ws + off);   off += 256 * 768 * 4;        // 786432
  float* qk_g        = (float*)(ws + off); off += 256 * 8 * 256 * 4;    // 2097152
  float* qbk_g       = (float*)(ws + off); off += 256 * 8 * 4;          // 8192
  float* qksum_g     = (float*)(ws + off); off += 256 * 256 * 4;        // 262144
  float* fbar_part   = (float*)(ws + off); off += 256 * 2 * 8 * 256 * 4;// 4194304
  float* expsum_part = (float*)(ws + off); off += 256 * 2 * 8 * 4;      // 16384
  float* stat_part   = (float*)(ws + off); off += 256 * 2 * 2 * 4;      // 4096
  float* aff2_g      = (float*)(ws + off); off += 256 * 768 * 4;        // 786432

  float* out_f = (float*)d_out;  // [0,65536) slots_new, [65536,262144) norm_aff

  topk_kernel<<<NSLOT, 1024, 0, stream>>>(curio, feat_sel);
  qproj_kernel<<<NSLOT, 256, 0, stream>>>(slots, ipw, ipb, qk_g, qbk_g, qksum_g);
  aff_pv_kernel<<<NSLOT * 2, 512, 0, stream>>>(features, posenc, batch_idx, feat_sel,
                                               qk_g, qbk_g, qksum_g, fbar_part,
                                               expsum_part, stat_part, aff2_g);
  finish_kernel<<<NSLOT, 1024, 0, stream>>>(slots, expsum_part, stat_part, aff2_g,
                                            fbar_part, ipw, ipb, wout, bout, lnw, lnb,
                                            out_f, out_f + 65536);
}

// Round 10
// 175.902 us; speedup vs baseline: 1.2436x; 1.0112x over previous
//
#include <hip/hip_runtime.h>
#include <math.h>

#define NSLOT 256
#define HWN   16384
#define D_    256
#define BB    4
#define NSEL  768
#define NPOS  512
#define NHEAD 8

// global->LDS DMA: 16B per lane; LDS dest is wave-uniform base (HW adds lane*16).
#define GLD_LDS(g, l)                                                      \
  __builtin_amdgcn_global_load_lds(                                        \
      (__attribute__((address_space(1))) void*)(g),                        \
      (__attribute__((address_space(3))) void*)(l), 16, 0, 0)

// Reduce 8 per-lane values over all 64 lanes simultaneously.
// Returns: full 64-lane sum of p[h], where h = (lane>>3)&7 for this lane.
__device__ __forceinline__ float reduce8x64(const float p[8], int lane) {
  float v[4];
#pragma unroll
  for (int h = 0; h < 4; h++) {
    float keep = (lane & 32) ? p[h + 4] : p[h];
    float send = (lane & 32) ? p[h] : p[h + 4];
    v[h] = keep + __shfl_xor(send, 32, 64);
  }
  float w[2];
#pragma unroll
  for (int h = 0; h < 2; h++) {
    float keep = (lane & 16) ? v[h + 2] : v[h];
    float send = (lane & 16) ? v[h] : v[h + 2];
    w[h] = keep + __shfl_xor(send, 16, 64);
  }
  float r;
  {
    float keep = (lane & 8) ? w[1] : w[0];
    float send = (lane & 8) ? w[0] : w[1];
    r = keep + __shfl_xor(send, 8, 64);
  }
  r += __shfl_xor(r, 4, 64);
  r += __shfl_xor(r, 2, 64);
  r += __shfl_xor(r, 1, 64);
  return r;
}

// ---------------- Kernel A: per-slot top-768 stable select (1024 thr) ----------------
__global__ __launch_bounds__(1024) void topk_kernel(const float* __restrict__ curio,
                                                    int* __restrict__ feat_sel) {
  __shared__ unsigned int hist[4096];
  __shared__ unsigned int wsum[16];
  __shared__ unsigned long long skey[2048];
  __shared__ int sBstar;
  __shared__ unsigned int sCount;
  int s = blockIdx.x;
  int t = threadIdx.x;
  int wave = t >> 6, lane = t & 63;
  const float* row = curio + (size_t)s * HWN;

  for (int i = t; i < 4096; i += 1024) hist[i] = 0;
  if (t == 0) sCount = 0;
  __syncthreads();
  for (int j = t; j < HWN; j += 1024) {
    unsigned int bits = __float_as_uint(row[j]);   // values in [0,1): bits monotone
    atomicAdd(&hist[bits >> 18], 1u);
  }
  __syncthreads();
  unsigned int cs = hist[t * 4] + hist[t * 4 + 1] + hist[t * 4 + 2] + hist[t * 4 + 3];
  unsigned int v = cs;
#pragma unroll
  for (int off = 1; off < 64; off <<= 1) {
    unsigned int u = __shfl_down(v, off, 64);
    if (lane + off < 64) v += u;       // suffix over lanes >= lane (this wave)
  }
  if (lane == 0) wsum[wave] = v;
  __syncthreads();
  unsigned int above = 0;
  for (int w2 = wave + 1; w2 < 16; w2++) above += wsum[w2];
  unsigned int sufAfter = above + (v - cs);
  if (sufAfter < NSEL && sufAfter + cs >= NSEL) {
    unsigned int local = sufAfter;
    for (int b = t * 4 + 3; b >= t * 4; b--) {
      unsigned int c = hist[b];
      if (local + c >= NSEL) { sBstar = b; break; }
      local += c;
    }
  }
  __syncthreads();
  int bstar = sBstar;
  for (int j = t; j < HWN; j += 1024) {
    unsigned int bits = __float_as_uint(row[j]);
    if ((int)(bits >> 18) >= bstar) {
      unsigned int pos = atomicAdd(&sCount, 1u);
      if (pos < 2048)
        skey[pos] = ((unsigned long long)bits << 14) | (unsigned long long)(16383 - j);
    }
  }
  __syncthreads();
  unsigned int M = sCount;
  int SZ = (M <= 1024) ? 1024 : 2048;
  for (int i = t; i < SZ; i += 1024) if (i >= (int)M) skey[i] = 0ull;
  for (int k = 2; k <= SZ; k <<= 1) {
    for (int j2 = k >> 1; j2 > 0; j2 >>= 1) {
      __syncthreads();
      for (int i = t; i < SZ; i += 1024) {
        int l = i ^ j2;
        if (l > i) {
          unsigned long long a = skey[i], b = skey[l];
          bool dir = ((i & k) == 0);
          if ((a < b) == dir) { skey[i] = b; skey[l] = a; }
        }
      }
    }
  }
  __syncthreads();
  for (int r = t; r < NSEL; r += 1024)
    feat_sel[s * NSEL + r] = 16383 - (int)(skey[r] & 16383ull);
}

// ---------------- Kernel B: q projection + qk = Wk^T q + qksum (per slot, 256 thr) ----------------
__global__ __launch_bounds__(256) void qproj_kernel(const float* __restrict__ slots,
                                                    const float* __restrict__ ipw,
                                                    const float* __restrict__ ipb,
                                                    float* __restrict__ qk_g,
                                                    float* __restrict__ qbk_g,
                                                    float* __restrict__ qksum_g) {
  __shared__ float srow[D_];
  __shared__ float qrow[D_];
  int s = blockIdx.x, t = threadIdx.x;
  srow[t] = slots[s * D_ + t];
  __syncthreads();
  {
    const float* wq = ipw + (size_t)t * D_;
    float acc = ipb[t];
    for (int d = 0; d < D_; d++) acc += srow[d] * wq[d];
    qrow[t] = acc * 0.17677669529663689f;  // 1/sqrt(32)
  }
  __syncthreads();
  float qsum = 0.f;
  for (int h = 0; h < NHEAD; h++) {
    const float* wkbase = ipw + (size_t)(D_ + h * 32) * D_ + t;
    float a = 0.f;
    for (int e = 0; e < 32; e++) a += qrow[h * 32 + e] * wkbase[(size_t)e * D_];
    qk_g[((size_t)s * NHEAD + h) * D_ + t] = a;
    qsum += a;
  }
  qksum_g[s * D_ + t] = qsum;
  if (t < NHEAD) {
    float a = 0.f;
    for (int e = 0; e < 32; e++) a += qrow[t * 32 + e] * ipb[D_ + t * 32 + e];
    qbk_g[s * NHEAD + t] = a;
  }
}

// ---------------- Kernel C: aff + fused PV partials, LDS-ring DMA pipeline ----------------
// grid = (slot, half), 512 thr. Block (s,half): local rows r=0..383 (global n = half+2r).
// Wave w owns 48 steps: step<32 -> pos row w*32+step; else neg row 256+w*16+(step-32).
// Per-wave private 3-slot LDS ring, global_load_lds DMA, counted vmcnt. No barriers in
// the main phase; no global ops in the loop (aff2 -> LDS, flushed at end).
__global__ __launch_bounds__(512, 2) void aff_pv_kernel(
    const float* __restrict__ features, const float* __restrict__ posenc,
    const int* __restrict__ batch_idx, const int* __restrict__ feat_sel,
    const float* __restrict__ qk_g, const float* __restrict__ qbk_g,
    const float* __restrict__ qksum_g,
    float* __restrict__ fbar_part,    // [256][2][8][256]
    float* __restrict__ expsum_part,  // [256][2][8]
    float* __restrict__ stat_part,    // [256][2][2]
    float* __restrict__ aff2_g) {     // [256][768]
  __shared__ float ring[8][3][2][D_]; // 48 KB: [wave][slot][f/p][dim]
  __shared__ float qks[NHEAD][D_];    // 8 KB
  __shared__ float fbar[NHEAD][D_];   // 8 KB
  __shared__ float a2buf[384];        // 1.5 KB
  __shared__ int   sfsel[384];        // 1.5 KB
  __shared__ float wtile[8][NHEAD];   // 256 B
  __shared__ float esums[8][NHEAD];
  __shared__ float sstat[8][2];
  __shared__ float qbkmean_s;

  int b = blockIdx.x, s = b >> 1, half = b & 1;
  int t = threadIdx.x, w = t >> 6, lane = t & 63;
  int bi = batch_idx[s];

  for (int i = t; i < NHEAD * D_; i += 512) {
    ((float*)qks)[i] = qk_g[(size_t)s * (NHEAD * D_) + i];
    ((float*)fbar)[i] = 0.f;
  }
  if (t < 384) sfsel[t] = feat_sel[s * NSEL + half + 2 * t];
  if (t == 0) {
    float m = 0.f;
    for (int h = 0; h < NHEAD; h++) m += qbk_g[s * NHEAD + h];
    qbkmean_s = m * 0.125f;
  }
  __syncthreads();
  float qbkmean = qbkmean_s;
  const float4 qs4 = *(const float4*)&qksum_g[s * D_ + lane * 4];
  size_t lofs = (size_t)(lane * 4);
  int lane4 = lane * 4;

  float acc[NHEAD][4];
#pragma unroll
  for (int h = 0; h < NHEAD; h++)
#pragma unroll
    for (int c = 0; c < 4; c++) acc[h][c] = 0.f;
  float esum = 0.f;  // valid on lanes with (lane&7)==0; head = lane>>3

  // DMA issue for step j into slot j%3 (slot passed statically by callers)
  auto ISSUE = [&](int j, int slot) {
    int r = (j < 32) ? (w * 32 + j) : (256 + w * 16 + (j - 32));
    size_t gb = ((size_t)sfsel[r] * BB + bi) * D_ + lofs;
    GLD_LDS(features + gb, &ring[w][slot][0][0]);
    GLD_LDS(posenc + gb, &ring[w][slot][1][0]);
  };

  auto BODY = [&](int i, int slot) {
    const float4 f = *(const float4*)&ring[w][slot][0][lane4];
    const float4 p = *(const float4*)&ring[w][slot][1][lane4];
    float4 k;
    k.x = f.x + p.x; k.y = f.y + p.y; k.z = f.z + p.z; k.w = f.w + p.w;
    asm volatile("" ::: "memory");  // ring reads consumed before slot reuse DMA
    if (i + 3 < 48) ISSUE(i + 3, slot);  // (i+3)%3 == i%3 == slot
    if (i < 32) {
      int r = w * 32 + i;
      float pp[NHEAD];
#pragma unroll
      for (int h = 0; h < NHEAD; h++) {
        const float4 qw = *(const float4*)&qks[h][lane4];
        pp[h] = k.x * qw.x + k.y * qw.y + k.z * qw.z + k.w * qw.w;
      }
      float rs = reduce8x64(pp, lane);
      float e = __expf(rs);
      if ((lane & 7) == 0) {
        wtile[w][lane >> 3] = e;
        esum += e;
      }
      float ts = rs;
      ts += __shfl_xor(ts, 8, 64);
      ts += __shfl_xor(ts, 16, 64);
      ts += __shfl_xor(ts, 32, 64);
      if (lane == 0) a2buf[r] = ts * 0.125f + qbkmean;
      const float4 w0 = *(const float4*)&wtile[w][0];
      const float4 w1 = *(const float4*)&wtile[w][4];
      acc[0][0] += w0.x * f.x; acc[0][1] += w0.x * f.y; acc[0][2] += w0.x * f.z; acc[0][3] += w0.x * f.w;
      acc[1][0] += w0.y * f.x; acc[1][1] += w0.y * f.y; acc[1][2] += w0.y * f.z; acc[1][3] += w0.y * f.w;
      acc[2][0] += w0.z * f.x; acc[2][1] += w0.z * f.y; acc[2][2] += w0.z * f.z; acc[2][3] += w0.z * f.w;
      acc[3][0] += w0.w * f.x; acc[3][1] += w0.w * f.y; acc[3][2] += w0.w * f.z; acc[3][3] += w0.w * f.w;
      acc[4][0] += w1.x * f.x; acc[4][1] += w1.x * f.y; acc[4][2] += w1.x * f.z; acc[4][3] += w1.x * f.w;
      acc[5][0] += w1.y * f.x; acc[5][1] += w1.y * f.y; acc[5][2] += w1.y * f.z; acc[5][3] += w1.y * f.w;
      acc[6][0] += w1.z * f.x; acc[6][1] += w1.z * f.y; acc[6][2] += w1.z * f.z; acc[6][3] += w1.z * f.w;
      acc[7][0] += w1.w * f.x; acc[7][1] += w1.w * f.y; acc[7][2] += w1.w * f.z; acc[7][3] += w1.w * f.w;
    } else {
      int r = 256 + w * 16 + (i - 32);
      float spp = k.x * qs4.x + k.y * qs4.y + k.z * qs4.z + k.w * qs4.w;
#pragma unroll
      for (int off = 1; off < 64; off <<= 1) spp += __shfl_xor(spp, off, 64);
      if (lane == 0) a2buf[r] = spp * 0.125f + qbkmean;
    }
  };

  // prologue: stage steps 0,1,2 (6 DMA ops outstanding)
  ISSUE(0, 0);
  ISSUE(1, 1);
  ISSUE(2, 2);
  // main: 45 steps (15 x 3, static slots); entering step i, outstanding = 6;
  // vmcnt(4) -> step i's 2 ops complete.
  for (int i0 = 0; i0 < 45; i0 += 3) {
    asm volatile("s_waitcnt vmcnt(4)" ::: "memory");
    BODY(i0, 0);
    asm volatile("s_waitcnt vmcnt(4)" ::: "memory");
    BODY(i0 + 1, 1);
    asm volatile("s_waitcnt vmcnt(4)" ::: "memory");
    BODY(i0 + 2, 2);
  }
  // tail: steps 45,46,47 issue nothing; outstanding counts 6 -> 4 -> 2
  asm volatile("s_waitcnt vmcnt(4)" ::: "memory");
  BODY(45, 0);
  asm volatile("s_waitcnt vmcnt(2)" ::: "memory");
  BODY(46, 1);
  asm volatile("s_waitcnt vmcnt(0)" ::: "memory");
  BODY(47, 2);

  // ---- combine partials
  if ((lane & 7) == 0) esums[w][lane >> 3] = esum;
#pragma unroll
  for (int h = 0; h < NHEAD; h++) {
    atomicAdd(&fbar[h][lane4 + 0], acc[h][0]);
    atomicAdd(&fbar[h][lane4 + 1], acc[h][1]);
    atomicAdd(&fbar[h][lane4 + 2], acc[h][2]);
    atomicAdd(&fbar[h][lane4 + 3], acc[h][3]);
  }
  __syncthreads();

  // stats over a2buf (all 384 local rows)
  {
    float v = (t < 384) ? a2buf[t] : 0.f;
    float ls = v, lq = v * v;
#pragma unroll
    for (int off = 32; off >= 1; off >>= 1) { ls += __shfl_xor(ls, off, 64); lq += __shfl_xor(lq, off, 64); }
    if (lane == 0) { sstat[w][0] = ls; sstat[w][1] = lq; }
  }
  __syncthreads();
  if (t < NHEAD) {
    float e2 = 0.f;
    for (int w2 = 0; w2 < 8; w2++) e2 += esums[w2][t];
    expsum_part[b * NHEAD + t] = e2;
  } else if (t == NHEAD) {
    float a = 0.f, q = 0.f;
    for (int w2 = 0; w2 < 8; w2++) { a += sstat[w2][0]; q += sstat[w2][1]; }
    stat_part[b * 2 + 0] = a;
    stat_part[b * 2 + 1] = q;
  }
  if (t < 384) aff2_g[s * NSEL + half + 2 * t] = a2buf[t];
  ((float4*)(fbar_part + (size_t)b * (NHEAD * D_)))[t] = ((float4*)fbar)[t];
}

// ---------------- Kernel D: combine partials + Wv + out-proj + LN + norm_aff ----------------
__global__ __launch_bounds__(1024) void finish_kernel(
    const float* __restrict__ slots,
    const float* __restrict__ expsum_part, const float* __restrict__ stat_part,
    const float* __restrict__ aff2_g, const float* __restrict__ fbar_part,
    const float* __restrict__ ipw, const float* __restrict__ ipb,
    const float* __restrict__ wout, const float* __restrict__ bout,
    const float* __restrict__ lnw, const float* __restrict__ lnb,
    float* __restrict__ slots_new, float* __restrict__ norm_aff) {
  __shared__ float fbar[NHEAD][D_];
  __shared__ float srow[D_];
  __shared__ float outv[D_];
  __shared__ float pq[1024];
  __shared__ float redS[4], redQ[4];
  int s = blockIdx.x, t = threadIdx.x, wave = t >> 6, lane = t & 63;

  // LN stats for norm_aff (uniform loads)
  float st0 = stat_part[s * 4 + 0] + stat_part[s * 4 + 2];
  float st1 = stat_part[s * 4 + 1] + stat_part[s * 4 + 3];
  float mean_a = st0 * (1.0f / NSEL);
  float var_a = st1 * (1.0f / NSEL) - mean_a * mean_a;
  float rstd_a = rsqrtf(var_a + 1e-5f);
  if (t < NSEL) norm_aff[(size_t)t * NSLOT + s] = (aff2_g[s * NSEL + t] - mean_a) * rstd_a;

  if (t < 512) {
    int h = t >> 6;  // fbar layout [8][256]: 64 float4s per head
    float inv = 1.0f / (expsum_part[s * 16 + h] + expsum_part[s * 16 + 8 + h]);
    const float4 a = ((const float4*)(fbar_part + (size_t)s * 4096))[t];
    const float4 c = ((const float4*)(fbar_part + (size_t)s * 4096 + 2048))[t];
    float4 r;
    r.x = (a.x + c.x) * inv; r.y = (a.y + c.y) * inv;
    r.z = (a.z + c.z) * inv; r.w = (a.w + c.w) * inv;
    ((float4*)fbar)[t] = r;
  }
  if (t < 64) ((float4*)srow)[t] = ((const float4*)(slots + (size_t)s * D_))[t];
  __syncthreads();

  // out = Wv . fbar(h) + bv  (quarter-dots)
  {
    int o = t >> 2, part = t & 3, h = o >> 5;
    const float4* wv = (const float4*)(ipw + (size_t)(2 * D_ + o) * D_ + part * 64);
    float a = 0.f;
#pragma unroll
    for (int i = 0; i < 16; i++) {
      float4 w = wv[i];
      int d = part * 64 + i * 4;
      a += fbar[h][d] * w.x + fbar[h][d + 1] * w.y + fbar[h][d + 2] * w.z + fbar[h][d + 3] * w.w;
    }
    pq[t] = a;
  }
  __syncthreads();
  if (t < D_)
    outv[t] = pq[t * 4] + pq[t * 4 + 1] + pq[t * 4 + 2] + pq[t * 4 + 3] + ipb[2 * D_ + t];
  __syncthreads();

  // slots_new = LN(srow + Wout.outv + bout) * lnw + lnb
  {
    int o = t >> 2, part = t & 3;
    const float4* w4 = (const float4*)(wout + (size_t)o * D_ + part * 64);
    float a = 0.f;
#pragma unroll
    for (int i = 0; i < 16; i++) {
      float4 w = w4[i];
      int d = part * 64 + i * 4;
      a += outv[d] * w.x + outv[d + 1] * w.y + outv[d + 2] * w.z + outv[d + 3] * w.w;
    }
    pq[t] = a;
  }
  __syncthreads();
  float v = 0.f;
  if (t < D_) {
    v = srow[t] + pq[t * 4] + pq[t * 4 + 1] + pq[t * 4 + 2] + pq[t * 4 + 3] + bout[t];
    float ls = v, lq = v * v;
#pragma unroll
    for (int off = 32; off >= 1; off >>= 1) { ls += __shfl_xor(ls, off, 64); lq += __shfl_xor(lq, off, 64); }
    if (lane == 0) { redS[wave] = ls; redQ[wave] = lq; }
  }
  __syncthreads();
  if (t < D_) {
    float tots = redS[0] + redS[1] + redS[2] + redS[3];
    float totq = redQ[0] + redQ[1] + redQ[2] + redQ[3];
    float mean = tots * (1.0f / D_);
    float var = totq * (1.0f / D_) - mean * mean;
    float rstd = rsqrtf(var + 1e-5f);
    slots_new[s * D_ + t] = (v - mean) * rstd * lnw[t] + lnb[t];
  }
}

extern "C" void kernel_launch(void* const* d_in, const int* in_sizes, int n_in,
                              void* d_out, int out_size, void* d_ws, size_t ws_size,
                              hipStream_t stream) {
  const float* slots    = (const float*)d_in[0];
  const float* features = (const float*)d_in[1];
  const float* posenc   = (const float*)d_in[2];
  const float* curio    = (const float*)d_in[3];
  const int*   batch_idx= (const int*)d_in[4];
  const float* ipw      = (const float*)d_in[5];
  const float* ipb      = (const float*)d_in[6];
  const float* wout     = (const float*)d_in[7];
  const float* bout     = (const float*)d_in[8];
  const float* lnw      = (const float*)d_in[9];
  const float* lnb      = (const float*)d_in[10];

  char* ws = (char*)d_ws;
  size_t off = 0;
  int*   feat_sel    = (int*)(ws + off);   off += 256 * 768 * 4;        // 786432
  float* qk_g        = (float*)(ws + off); off += 256 * 8 * 256 * 4;    // 2097152
  float* qbk_g       = (float*)(ws + off); off += 256 * 8 * 4;          // 8192
  float* qksum_g     = (float*)(ws + off); off += 256 * 256 * 4;        // 262144
  float* fbar_part   = (float*)(ws + off); off += 256 * 2 * 8 * 256 * 4;// 4194304
  float* expsum_part = (float*)(ws + off); off += 256 * 2 * 8 * 4;      // 16384
  float* stat_part   = (float*)(ws + off); off += 256 * 2 * 2 * 4;      // 4096
  float* aff2_g      = (float*)(ws + off); off += 256 * 768 * 4;        // 786432

  float* out_f = (float*)d_out;  // [0,65536) slots_new, [65536,262144) norm_aff

  topk_kernel<<<NSLOT, 1024, 0, stream>>>(curio, feat_sel);
  qproj_kernel<<<NSLOT, 256, 0, stream>>>(slots, ipw, ipb, qk_g, qbk_g, qksum_g);
  aff_pv_kernel<<<NSLOT * 2, 512, 0, stream>>>(features, posenc, batch_idx, feat_sel,
                                               qk_g, qbk_g, qksum_g, fbar_part,
                                               expsum_part, stat_part, aff2_g);
  finish_kernel<<<NSLOT, 1024, 0, stream>>>(slots, expsum_part, stat_part, aff2_g,
                                            fbar_part, ipw, ipb, wout, bout, lnw, lnb,
                                            out_f, out_f + 65536);
}

// Round 11
// 174.823 us; speedup vs baseline: 1.2513x; 1.0062x over previous
//
#include <hip/hip_runtime.h>
#include <math.h>

#define NSLOT 256
#define HWN   16384
#define D_    256
#define BB    4
#define NSEL  768
#define NPOS  512
#define NHEAD 8

// global->LDS DMA: 16B per lane; LDS dest is wave-uniform base (HW adds lane*16).
#define GLD_LDS(g, l)                                                      \
  __builtin_amdgcn_global_load_lds(                                        \
      (__attribute__((address_space(1))) void*)(g),                        \
      (__attribute__((address_space(3))) void*)(l), 16, 0, 0)

// Reduce 8 per-lane values over all 64 lanes simultaneously.
// Returns: full 64-lane sum of p[h], where h = (lane>>3)&7 for this lane.
__device__ __forceinline__ float reduce8x64(const float p[8], int lane) {
  float v[4];
#pragma unroll
  for (int h = 0; h < 4; h++) {
    float keep = (lane & 32) ? p[h + 4] : p[h];
    float send = (lane & 32) ? p[h] : p[h + 4];
    v[h] = keep + __shfl_xor(send, 32, 64);
  }
  float w[2];
#pragma unroll
  for (int h = 0; h < 2; h++) {
    float keep = (lane & 16) ? v[h + 2] : v[h];
    float send = (lane & 16) ? v[h] : v[h + 2];
    w[h] = keep + __shfl_xor(send, 16, 64);
  }
  float r;
  {
    float keep = (lane & 8) ? w[1] : w[0];
    float send = (lane & 8) ? w[0] : w[1];
    r = keep + __shfl_xor(send, 8, 64);
  }
  r += __shfl_xor(r, 4, 64);
  r += __shfl_xor(r, 2, 64);
  r += __shfl_xor(r, 1, 64);
  return r;
}

// ---------------- Kernel A: per-slot top-768 stable select (1024 thr) ----------------
__global__ __launch_bounds__(1024) void topk_kernel(const float* __restrict__ curio,
                                                    int* __restrict__ feat_sel) {
  __shared__ unsigned int hist[4096];
  __shared__ unsigned int wsum[16];
  __shared__ unsigned long long skey[2048];
  __shared__ int sBstar;
  __shared__ unsigned int sCount;
  int s = blockIdx.x;
  int t = threadIdx.x;
  int wave = t >> 6, lane = t & 63;
  const float* row = curio + (size_t)s * HWN;

  for (int i = t; i < 4096; i += 1024) hist[i] = 0;
  if (t == 0) sCount = 0;
  __syncthreads();
  for (int j = t; j < HWN; j += 1024) {
    unsigned int bits = __float_as_uint(row[j]);   // values in [0,1): bits monotone
    atomicAdd(&hist[bits >> 18], 1u);
  }
  __syncthreads();
  unsigned int cs = hist[t * 4] + hist[t * 4 + 1] + hist[t * 4 + 2] + hist[t * 4 + 3];
  unsigned int v = cs;
#pragma unroll
  for (int off = 1; off < 64; off <<= 1) {
    unsigned int u = __shfl_down(v, off, 64);
    if (lane + off < 64) v += u;       // suffix over lanes >= lane (this wave)
  }
  if (lane == 0) wsum[wave] = v;
  __syncthreads();
  unsigned int above = 0;
  for (int w2 = wave + 1; w2 < 16; w2++) above += wsum[w2];
  unsigned int sufAfter = above + (v - cs);
  if (sufAfter < NSEL && sufAfter + cs >= NSEL) {
    unsigned int local = sufAfter;
    for (int b = t * 4 + 3; b >= t * 4; b--) {
      unsigned int c = hist[b];
      if (local + c >= NSEL) { sBstar = b; break; }
      local += c;
    }
  }
  __syncthreads();
  int bstar = sBstar;
  for (int j = t; j < HWN; j += 1024) {
    unsigned int bits = __float_as_uint(row[j]);
    if ((int)(bits >> 18) >= bstar) {
      unsigned int pos = atomicAdd(&sCount, 1u);
      if (pos < 2048)
        skey[pos] = ((unsigned long long)bits << 14) | (unsigned long long)(16383 - j);
    }
  }
  __syncthreads();
  unsigned int M = sCount;
  int SZ = (M <= 1024) ? 1024 : 2048;
  for (int i = t; i < SZ; i += 1024) if (i >= (int)M) skey[i] = 0ull;
  for (int k = 2; k <= SZ; k <<= 1) {
    for (int j2 = k >> 1; j2 > 0; j2 >>= 1) {
      __syncthreads();
      for (int i = t; i < SZ; i += 1024) {
        int l = i ^ j2;
        if (l > i) {
          unsigned long long a = skey[i], b = skey[l];
          bool dir = ((i & k) == 0);
          if ((a < b) == dir) { skey[i] = b; skey[l] = a; }
        }
      }
    }
  }
  __syncthreads();
  for (int r = t; r < NSEL; r += 1024)
    feat_sel[s * NSEL + r] = 16383 - (int)(skey[r] & 16383ull);
}

// ---------------- Kernel B: q projection + qk = Wk^T q + qksum (per slot, 256 thr) ----------------
__global__ __launch_bounds__(256) void qproj_kernel(const float* __restrict__ slots,
                                                    const float* __restrict__ ipw,
                                                    const float* __restrict__ ipb,
                                                    float* __restrict__ qk_g,
                                                    float* __restrict__ qbk_g,
                                                    float* __restrict__ qksum_g) {
  __shared__ float srow[D_];
  __shared__ float qrow[D_];
  int s = blockIdx.x, t = threadIdx.x;
  srow[t] = slots[s * D_ + t];
  __syncthreads();
  {
    const float* wq = ipw + (size_t)t * D_;
    float acc = ipb[t];
    for (int d = 0; d < D_; d++) acc += srow[d] * wq[d];
    qrow[t] = acc * 0.17677669529663689f;  // 1/sqrt(32)
  }
  __syncthreads();
  float qsum = 0.f;
  for (int h = 0; h < NHEAD; h++) {
    const float* wkbase = ipw + (size_t)(D_ + h * 32) * D_ + t;
    float a = 0.f;
    for (int e = 0; e < 32; e++) a += qrow[h * 32 + e] * wkbase[(size_t)e * D_];
    qk_g[((size_t)s * NHEAD + h) * D_ + t] = a;
    qsum += a;
  }
  qksum_g[s * D_ + t] = qsum;
  if (t < NHEAD) {
    float a = 0.f;
    for (int e = 0; e < 32; e++) a += qrow[t * 32 + e] * ipb[D_ + t * 32 + e];
    qbk_g[s * NHEAD + t] = a;
  }
}

// ---------------- Kernel C: aff + fused PV partials, LDS-ring DMA pipeline ----------------
// grid = (slot, half), 512 thr. Block (s,half): local rows r=0..383 (global n = half+2r).
// Wave w owns 48 steps: step<32 -> pos row w*32+step; else neg row 256+w*16+(step-32).
// Per-wave private 2-SLOT LDS ring (depth 2) -> block LDS ~53 KB -> 3 blocks/CU
// (R10 lesson: depth-3 ring at 2 blocks/CU was latency-starved; trade depth for waves).
__global__ __launch_bounds__(512, 2) void aff_pv_kernel(
    const float* __restrict__ features, const float* __restrict__ posenc,
    const int* __restrict__ batch_idx, const int* __restrict__ feat_sel,
    const float* __restrict__ qk_g, const float* __restrict__ qbk_g,
    const float* __restrict__ qksum_g,
    float* __restrict__ fbar_part,    // [256][2][8][256]
    float* __restrict__ expsum_part,  // [256][2][8]
    float* __restrict__ stat_part,    // [256][2][2]
    float* __restrict__ aff2_g) {     // [256][768]
  __shared__ float ring[8][2][2][D_]; // 32 KB: [wave][slot][f/p][dim]
  __shared__ float qks[NHEAD][D_];    // 8 KB
  __shared__ float fbar[NHEAD][D_];   // 8 KB
  __shared__ float a2buf[384];        // 1.5 KB
  __shared__ int   sfsel[384];        // 1.5 KB
  __shared__ float wtile[8][NHEAD];   // 256 B
  __shared__ float esums[8][NHEAD];
  __shared__ float sstat[8][2];
  __shared__ float qbkmean_s;

  int b = blockIdx.x, s = b >> 1, half = b & 1;
  int t = threadIdx.x, w = t >> 6, lane = t & 63;
  int bi = batch_idx[s];

  for (int i = t; i < NHEAD * D_; i += 512) {
    ((float*)qks)[i] = qk_g[(size_t)s * (NHEAD * D_) + i];
    ((float*)fbar)[i] = 0.f;
  }
  if (t < 384) sfsel[t] = feat_sel[s * NSEL + half + 2 * t];
  if (t == 0) {
    float m = 0.f;
    for (int h = 0; h < NHEAD; h++) m += qbk_g[s * NHEAD + h];
    qbkmean_s = m * 0.125f;
  }
  __syncthreads();
  float qbkmean = qbkmean_s;
  const float4 qs4 = *(const float4*)&qksum_g[s * D_ + lane * 4];
  size_t lofs = (size_t)(lane * 4);
  int lane4 = lane * 4;

  float acc[NHEAD][4];
#pragma unroll
  for (int h = 0; h < NHEAD; h++)
#pragma unroll
    for (int c = 0; c < 4; c++) acc[h][c] = 0.f;
  float esum = 0.f;  // valid on lanes with (lane&7)==0; head = lane>>3

  // DMA issue for step j into slot j&1 (slot passed statically by callers)
  auto ISSUE = [&](int j, int slot) {
    int r = (j < 32) ? (w * 32 + j) : (256 + w * 16 + (j - 32));
    size_t gb = ((size_t)sfsel[r] * BB + bi) * D_ + lofs;
    GLD_LDS(features + gb, &ring[w][slot][0][0]);
    GLD_LDS(posenc + gb, &ring[w][slot][1][0]);
  };

  auto BODY = [&](int i, int slot) {
    const float4 f = *(const float4*)&ring[w][slot][0][lane4];
    const float4 p = *(const float4*)&ring[w][slot][1][lane4];
    float4 k;
    k.x = f.x + p.x; k.y = f.y + p.y; k.z = f.z + p.z; k.w = f.w + p.w;
    asm volatile("" ::: "memory");  // ring reads consumed before slot reuse DMA
    if (i + 2 < 48) ISSUE(i + 2, slot);  // (i+2)&1 == i&1 == slot
    if (i < 32) {
      int r = w * 32 + i;
      float pp[NHEAD];
#pragma unroll
      for (int h = 0; h < NHEAD; h++) {
        const float4 qw = *(const float4*)&qks[h][lane4];
        pp[h] = k.x * qw.x + k.y * qw.y + k.z * qw.z + k.w * qw.w;
      }
      float rs = reduce8x64(pp, lane);
      float e = __expf(rs);
      if ((lane & 7) == 0) {
        wtile[w][lane >> 3] = e;
        esum += e;
      }
      float ts = rs;
      ts += __shfl_xor(ts, 8, 64);
      ts += __shfl_xor(ts, 16, 64);
      ts += __shfl_xor(ts, 32, 64);
      if (lane == 0) a2buf[r] = ts * 0.125f + qbkmean;
      const float4 w0 = *(const float4*)&wtile[w][0];
      const float4 w1 = *(const float4*)&wtile[w][4];
      acc[0][0] += w0.x * f.x; acc[0][1] += w0.x * f.y; acc[0][2] += w0.x * f.z; acc[0][3] += w0.x * f.w;
      acc[1][0] += w0.y * f.x; acc[1][1] += w0.y * f.y; acc[1][2] += w0.y * f.z; acc[1][3] += w0.y * f.w;
      acc[2][0] += w0.z * f.x; acc[2][1] += w0.z * f.y; acc[2][2] += w0.z * f.z; acc[2][3] += w0.z * f.w;
      acc[3][0] += w0.w * f.x; acc[3][1] += w0.w * f.y; acc[3][2] += w0.w * f.z; acc[3][3] += w0.w * f.w;
      acc[4][0] += w1.x * f.x; acc[4][1] += w1.x * f.y; acc[4][2] += w1.x * f.z; acc[4][3] += w1.x * f.w;
      acc[5][0] += w1.y * f.x; acc[5][1] += w1.y * f.y; acc[5][2] += w1.y * f.z; acc[5][3] += w1.y * f.w;
      acc[6][0] += w1.z * f.x; acc[6][1] += w1.z * f.y; acc[6][2] += w1.z * f.z; acc[6][3] += w1.z * f.w;
      acc[7][0] += w1.w * f.x; acc[7][1] += w1.w * f.y; acc[7][2] += w1.w * f.z; acc[7][3] += w1.w * f.w;
    } else {
      int r = 256 + w * 16 + (i - 32);
      float spp = k.x * qs4.x + k.y * qs4.y + k.z * qs4.z + k.w * qs4.w;
#pragma unroll
      for (int off = 1; off < 64; off <<= 1) spp += __shfl_xor(spp, off, 64);
      if (lane == 0) a2buf[r] = spp * 0.125f + qbkmean;
    }
  };

  // prologue: stage steps 0,1 (4 DMA ops outstanding)
  ISSUE(0, 0);
  ISSUE(1, 1);
  // main: entering body i (issued through step i+1), vmcnt(2) leaves only step
  // i+1's 2 ops outstanding -> step i complete. Bodies 0..45:
  for (int i0 = 0; i0 < 46; i0 += 2) {
    asm volatile("s_waitcnt vmcnt(2)" ::: "memory");
    BODY(i0, 0);
    asm volatile("s_waitcnt vmcnt(2)" ::: "memory");
    BODY(i0 + 1, 1);
  }
  // tail: body 46 (nothing to issue), body 47
  asm volatile("s_waitcnt vmcnt(2)" ::: "memory");
  BODY(46, 0);
  asm volatile("s_waitcnt vmcnt(0)" ::: "memory");
  BODY(47, 1);

  // ---- combine partials
  if ((lane & 7) == 0) esums[w][lane >> 3] = esum;
#pragma unroll
  for (int h = 0; h < NHEAD; h++) {
    atomicAdd(&fbar[h][lane4 + 0], acc[h][0]);
    atomicAdd(&fbar[h][lane4 + 1], acc[h][1]);
    atomicAdd(&fbar[h][lane4 + 2], acc[h][2]);
    atomicAdd(&fbar[h][lane4 + 3], acc[h][3]);
  }
  __syncthreads();

  // stats over a2buf (all 384 local rows)
  {
    float v = (t < 384) ? a2buf[t] : 0.f;
    float ls = v, lq = v * v;
#pragma unroll
    for (int off = 32; off >= 1; off >>= 1) { ls += __shfl_xor(ls, off, 64); lq += __shfl_xor(lq, off, 64); }
    if (lane == 0) { sstat[w][0] = ls; sstat[w][1] = lq; }
  }
  __syncthreads();
  if (t < NHEAD) {
    float e2 = 0.f;
    for (int w2 = 0; w2 < 8; w2++) e2 += esums[w2][t];
    expsum_part[b * NHEAD + t] = e2;
  } else if (t == NHEAD) {
    float a = 0.f, q = 0.f;
    for (int w2 = 0; w2 < 8; w2++) { a += sstat[w2][0]; q += sstat[w2][1]; }
    stat_part[b * 2 + 0] = a;
    stat_part[b * 2 + 1] = q;
  }
  if (t < 384) aff2_g[s * NSEL + half + 2 * t] = a2buf[t];
  ((float4*)(fbar_part + (size_t)b * (NHEAD * D_)))[t] = ((float4*)fbar)[t];
}

// ---------------- Kernel D: combine partials + Wv + out-proj + LN + norm_aff ----------------
__global__ __launch_bounds__(1024) void finish_kernel(
    const float* __restrict__ slots,
    const float* __restrict__ expsum_part, const float* __restrict__ stat_part,
    const float* __restrict__ aff2_g, const float* __restrict__ fbar_part,
    const float* __restrict__ ipw, const float* __restrict__ ipb,
    const float* __restrict__ wout, const float* __restrict__ bout,
    const float* __restrict__ lnw, const float* __restrict__ lnb,
    float* __restrict__ slots_new, float* __restrict__ norm_aff) {
  __shared__ float fbar[NHEAD][D_];
  __shared__ float srow[D_];
  __shared__ float outv[D_];
  __shared__ float pq[1024];
  __shared__ float redS[4], redQ[4];
  int s = blockIdx.x, t = threadIdx.x, wave = t >> 6, lane = t & 63;

  // LN stats for norm_aff (uniform loads)
  float st0 = stat_part[s * 4 + 0] + stat_part[s * 4 + 2];
  float st1 = stat_part[s * 4 + 1] + stat_part[s * 4 + 3];
  float mean_a = st0 * (1.0f / NSEL);
  float var_a = st1 * (1.0f / NSEL) - mean_a * mean_a;
  float rstd_a = rsqrtf(var_a + 1e-5f);
  if (t < NSEL) norm_aff[(size_t)t * NSLOT + s] = (aff2_g[s * NSEL + t] - mean_a) * rstd_a;

  if (t < 512) {
    int h = t >> 6;  // fbar layout [8][256]: 64 float4s per head
    float inv = 1.0f / (expsum_part[s * 16 + h] + expsum_part[s * 16 + 8 + h]);
    const float4 a = ((const float4*)(fbar_part + (size_t)s * 4096))[t];
    const float4 c = ((const float4*)(fbar_part + (size_t)s * 4096 + 2048))[t];
    float4 r;
    r.x = (a.x + c.x) * inv; r.y = (a.y + c.y) * inv;
    r.z = (a.z + c.z) * inv; r.w = (a.w + c.w) * inv;
    ((float4*)fbar)[t] = r;
  }
  if (t < 64) ((float4*)srow)[t] = ((const float4*)(slots + (size_t)s * D_))[t];
  __syncthreads();

  // out = Wv . fbar(h) + bv  (quarter-dots)
  {
    int o = t >> 2, part = t & 3, h = o >> 5;
    const float4* wv = (const float4*)(ipw + (size_t)(2 * D_ + o) * D_ + part * 64);
    float a = 0.f;
#pragma unroll
    for (int i = 0; i < 16; i++) {
      float4 w = wv[i];
      int d = part * 64 + i * 4;
      a += fbar[h][d] * w.x + fbar[h][d + 1] * w.y + fbar[h][d + 2] * w.z + fbar[h][d + 3] * w.w;
    }
    pq[t] = a;
  }
  __syncthreads();
  if (t < D_)
    outv[t] = pq[t * 4] + pq[t * 4 + 1] + pq[t * 4 + 2] + pq[t * 4 + 3] + ipb[2 * D_ + t];
  __syncthreads();

  // slots_new = LN(srow + Wout.outv + bout) * lnw + lnb
  {
    int o = t >> 2, part = t & 3;
    const float4* w4 = (const float4*)(wout + (size_t)o * D_ + part * 64);
    float a = 0.f;
#pragma unroll
    for (int i = 0; i < 16; i++) {
      float4 w = w4[i];
      int d = part * 64 + i * 4;
      a += outv[d] * w.x + outv[d + 1] * w.y + outv[d + 2] * w.z + outv[d + 3] * w.w;
    }
    pq[t] = a;
  }
  __syncthreads();
  float v = 0.f;
  if (t < D_) {
    v = srow[t] + pq[t * 4] + pq[t * 4 + 1] + pq[t * 4 + 2] + pq[t * 4 + 3] + bout[t];
    float ls = v, lq = v * v;
#pragma unroll
    for (int off = 32; off >= 1; off >>= 1) { ls += __shfl_xor(ls, off, 64); lq += __shfl_xor(lq, off, 64); }
    if (lane == 0) { redS[wave] = ls; redQ[wave] = lq; }
  }
  __syncthreads();
  if (t < D_) {
    float tots = redS[0] + redS[1] + redS[2] + redS[3];
    float totq = redQ[0] + redQ[1] + redQ[2] + redQ[3];
    float mean = tots * (1.0f / D_);
    float var = totq * (1.0f / D_) - mean * mean;
    float rstd = rsqrtf(var + 1e-5f);
    slots_new[s * D_ + t] = (v - mean) * rstd * lnw[t] + lnb[t];
  }
}

extern "C" void kernel_launch(void* const* d_in, const int* in_sizes, int n_in,
                              void* d_out, int out_size, void* d_ws, size_t ws_size,
                              hipStream_t stream) {
  const float* slots    = (const float*)d_in[0];
  const float* features = (const float*)d_in[1];
  const float* posenc   = (const float*)d_in[2];
  const float* curio    = (const float*)d_in[3];
  const int*   batch_idx= (const int*)d_in[4];
  const float* ipw      = (const float*)d_in[5];
  const float* ipb      = (const float*)d_in[6];
  const float* wout     = (const float*)d_in[7];
  const float* bout     = (const float*)d_in[8];
  const float* lnw      = (const float*)d_in[9];
  const float* lnb      = (const float*)d_in[10];

  char* ws = (char*)d_ws;
  size_t off = 0;
  int*   feat_sel    = (int*)(ws + off);   off += 256 * 768 * 4;        // 786432
  float* qk_g        = (float*)(ws + off); off += 256 * 8 * 256 * 4;    // 2097152
  float* qbk_g       = (float*)(ws + off); off += 256 * 8 * 4;          // 8192
  float* qksum_g     = (float*)(ws + off); off += 256 * 256 * 4;        // 262144
  float* fbar_part   = (float*)(ws + off); off += 256 * 2 * 8 * 256 * 4;// 4194304
  float* expsum_part = (float*)(ws + off); off += 256 * 2 * 8 * 4;      // 16384
  float* stat_part   = (float*)(ws + off); off += 256 * 2 * 2 * 4;      // 4096
  float* aff2_g      = (float*)(ws + off); off += 256 * 768 * 4;        // 786432

  float* out_f = (float*)d_out;  // [0,65536) slots_new, [65536,262144) norm_aff

  topk_kernel<<<NSLOT, 1024, 0, stream>>>(curio, feat_sel);
  qproj_kernel<<<NSLOT, 256, 0, stream>>>(slots, ipw, ipb, qk_g, qbk_g, qksum_g);
  aff_pv_kernel<<<NSLOT * 2, 512, 0, stream>>>(features, posenc, batch_idx, feat_sel,
                                               qk_g, qbk_g, qksum_g, fbar_part,
                                               expsum_part, stat_part, aff2_g);
  finish_kernel<<<NSLOT, 1024, 0, stream>>>(slots, expsum_part, stat_part, aff2_g,
                                            fbar_part, ipw, ipb, wout, bout, lnw, lnb,
                                            out_f, out_f + 65536);
}